// Round 3
// baseline (1314.322 us; speedup 1.0000x reference)
//
#include <hip/hip_runtime.h>
#include <hip/hip_bf16.h>
#include <math.h>
#include <stdint.h>

typedef __hip_bfloat16 bf16_t;
typedef __bf16 bf16x8 __attribute__((ext_vector_type(8)));
typedef float f32x4 __attribute__((ext_vector_type(4)));

#define MFMA_BF16(a, b, c) __builtin_amdgcn_mfma_f32_16x16x32_bf16((a), (b), (c), 0, 0, 0)

// Load 8 consecutive f32 and pack to 8 bf16 (one uint4 for ds_write b128).
__device__ __forceinline__ uint4 ld8_f32_bf16(const float* p) {
  const float4 x = *(const float4*)p;
  const float4 y = *(const float4*)(p + 4);
  union { bf16_t h[8]; uint4 u; } r;
  r.h[0] = __float2bfloat16(x.x); r.h[1] = __float2bfloat16(x.y);
  r.h[2] = __float2bfloat16(x.z); r.h[3] = __float2bfloat16(x.w);
  r.h[4] = __float2bfloat16(y.x); r.h[5] = __float2bfloat16(y.y);
  r.h[6] = __float2bfloat16(y.z); r.h[7] = __float2bfloat16(y.w);
  return r.u;
}

// C[m,n] = (sum_k A[m,k]*W[n,k] + bias[n]) * alpha.  A,W,bias f32; C bf16.
// 128x128 tile, BK=32, 256 threads = 4 waves (2x2 of 64x64 subtiles).
__global__ __launch_bounds__(256) void gemm_f32(const float* __restrict__ A,
                                                const float* __restrict__ W,
                                                const float* __restrict__ bias,
                                                bf16_t* __restrict__ C, float alpha) {
  const int K = 512, N = 512;
  __shared__ __align__(16) bf16_t As[128 * 32];
  __shared__ __align__(16) bf16_t Bs[128 * 32];
  const int tid = threadIdx.x;
  const int w = tid >> 6, lane = tid & 63;
  const int quad = lane >> 4, l16 = lane & 15;
  const int wm = (w >> 1) * 64, wn = (w & 1) * 64;
  const size_t m0 = (size_t)blockIdx.x * 128;
  const int n0 = blockIdx.y * 128;
  const float* Ab = A + m0 * K;
  const float* Wb = W + (size_t)n0 * K;
  const int r0 = tid >> 2;          // staging row (0..63)
  const int c0 = (tid & 3) * 8;     // staging col group (8 elems)
  f32x4 acc[4][4] = {};
  for (int k0 = 0; k0 < K; k0 += 32) {
    const uint4 a0 = ld8_f32_bf16(&Ab[(size_t)r0 * K + k0 + c0]);
    const uint4 a1 = ld8_f32_bf16(&Ab[(size_t)(r0 + 64) * K + k0 + c0]);
    const uint4 b0 = ld8_f32_bf16(&Wb[(size_t)r0 * K + k0 + c0]);
    const uint4 b1 = ld8_f32_bf16(&Wb[(size_t)(r0 + 64) * K + k0 + c0]);
    __syncthreads();  // prior iteration's LDS reads complete
    *(uint4*)&As[r0 * 32 + c0] = a0;
    *(uint4*)&As[(r0 + 64) * 32 + c0] = a1;
    *(uint4*)&Bs[r0 * 32 + c0] = b0;
    *(uint4*)&Bs[(r0 + 64) * 32 + c0] = b1;
    __syncthreads();
    bf16x8 af[4], bfr[4];
#pragma unroll
    for (int i = 0; i < 4; i++)
      af[i] = *(const bf16x8*)&As[(wm + i * 16 + l16) * 32 + quad * 8];
#pragma unroll
    for (int j = 0; j < 4; j++)
      bfr[j] = *(const bf16x8*)&Bs[(wn + j * 16 + l16) * 32 + quad * 8];
#pragma unroll
    for (int i = 0; i < 4; i++)
#pragma unroll
      for (int j = 0; j < 4; j++)
        acc[i][j] = MFMA_BF16(af[i], bfr[j], acc[i][j]);
  }
#pragma unroll
  for (int j = 0; j < 4; j++) {
    const int col = n0 + wn + j * 16 + l16;
    const float bv = bias[col];
#pragma unroll
    for (int i = 0; i < 4; i++) {
      const size_t row = m0 + wm + i * 16 + quad * 4;
#pragma unroll
      for (int v = 0; v < 4; v++) {
        const float x = (acc[i][j][v] + bv) * alpha;
        C[(row + v) * N + col] = __float2bfloat16(x);
      }
    }
  }
}

// Same GEMM but A is bf16 (workspace tensor), W/bias f32, C bf16.
__global__ __launch_bounds__(256) void gemm_abf16(const bf16_t* __restrict__ A,
                                                  const float* __restrict__ W,
                                                  const float* __restrict__ bias,
                                                  bf16_t* __restrict__ C) {
  const int K = 512, N = 512;
  __shared__ __align__(16) bf16_t As[128 * 32];
  __shared__ __align__(16) bf16_t Bs[128 * 32];
  const int tid = threadIdx.x;
  const int w = tid >> 6, lane = tid & 63;
  const int quad = lane >> 4, l16 = lane & 15;
  const int wm = (w >> 1) * 64, wn = (w & 1) * 64;
  const size_t m0 = (size_t)blockIdx.x * 128;
  const int n0 = blockIdx.y * 128;
  const bf16_t* Ab = A + m0 * K;
  const float* Wb = W + (size_t)n0 * K;
  const int r0 = tid >> 2;
  const int c0 = (tid & 3) * 8;
  f32x4 acc[4][4] = {};
  for (int k0 = 0; k0 < K; k0 += 32) {
    const uint4 a0 = *(const uint4*)&Ab[(size_t)r0 * K + k0 + c0];
    const uint4 a1 = *(const uint4*)&Ab[(size_t)(r0 + 64) * K + k0 + c0];
    const uint4 b0 = ld8_f32_bf16(&Wb[(size_t)r0 * K + k0 + c0]);
    const uint4 b1 = ld8_f32_bf16(&Wb[(size_t)(r0 + 64) * K + k0 + c0]);
    __syncthreads();
    *(uint4*)&As[r0 * 32 + c0] = a0;
    *(uint4*)&As[(r0 + 64) * 32 + c0] = a1;
    *(uint4*)&Bs[r0 * 32 + c0] = b0;
    *(uint4*)&Bs[(r0 + 64) * 32 + c0] = b1;
    __syncthreads();
    bf16x8 af[4], bfr[4];
#pragma unroll
    for (int i = 0; i < 4; i++)
      af[i] = *(const bf16x8*)&As[(wm + i * 16 + l16) * 32 + quad * 8];
#pragma unroll
    for (int j = 0; j < 4; j++)
      bfr[j] = *(const bf16x8*)&Bs[(wn + j * 16 + l16) * 32 + quad * 8];
#pragma unroll
    for (int i = 0; i < 4; i++)
#pragma unroll
      for (int j = 0; j < 4; j++)
        acc[i][j] = MFMA_BF16(af[i], bfr[j], acc[i][j]);
  }
#pragma unroll
  for (int j = 0; j < 4; j++) {
    const int col = n0 + wn + j * 16 + l16;
    const float bv = bias[col];
#pragma unroll
    for (int i = 0; i < 4; i++) {
      const size_t row = m0 + wm + i * 16 + quad * 4;
#pragma unroll
      for (int v = 0; v < 4; v++) {
        const float x = acc[i][j][v] + bv;
        C[(row + v) * N + col] = __float2bfloat16(x);
      }
    }
  }
}

// Gating: out = tanh(A@Wi^T + bi) * sigmoid(A@Wg^T + bg). A bf16; Wi/Wg/bi/bg f32; out f32.
__global__ __launch_bounds__(256) void gemm_gate(const bf16_t* __restrict__ A,
                                                 const float* __restrict__ Wi,
                                                 const float* __restrict__ bi,
                                                 const float* __restrict__ Wg,
                                                 const float* __restrict__ bg,
                                                 float* __restrict__ C) {
  const int K = 512, N = 512;
  __shared__ __align__(16) bf16_t As[128 * 32];
  __shared__ __align__(16) bf16_t Bi[128 * 32];
  __shared__ __align__(16) bf16_t Bg[128 * 32];
  const int tid = threadIdx.x;
  const int w = tid >> 6, lane = tid & 63;
  const int quad = lane >> 4, l16 = lane & 15;
  const int wm = (w >> 1) * 64, wn = (w & 1) * 64;
  const size_t m0 = (size_t)blockIdx.x * 128;
  const int n0 = blockIdx.y * 128;
  const bf16_t* Ab = A + m0 * K;
  const float* Wib = Wi + (size_t)n0 * K;
  const float* Wgb = Wg + (size_t)n0 * K;
  const int r0 = tid >> 2;
  const int c0 = (tid & 3) * 8;
  f32x4 ai[4][4] = {};
  f32x4 ag[4][4] = {};
  for (int k0 = 0; k0 < K; k0 += 32) {
    const uint4 a0 = *(const uint4*)&Ab[(size_t)r0 * K + k0 + c0];
    const uint4 a1 = *(const uint4*)&Ab[(size_t)(r0 + 64) * K + k0 + c0];
    const uint4 i0 = ld8_f32_bf16(&Wib[(size_t)r0 * K + k0 + c0]);
    const uint4 i1 = ld8_f32_bf16(&Wib[(size_t)(r0 + 64) * K + k0 + c0]);
    const uint4 g0 = ld8_f32_bf16(&Wgb[(size_t)r0 * K + k0 + c0]);
    const uint4 g1 = ld8_f32_bf16(&Wgb[(size_t)(r0 + 64) * K + k0 + c0]);
    __syncthreads();
    *(uint4*)&As[r0 * 32 + c0] = a0;
    *(uint4*)&As[(r0 + 64) * 32 + c0] = a1;
    *(uint4*)&Bi[r0 * 32 + c0] = i0;
    *(uint4*)&Bi[(r0 + 64) * 32 + c0] = i1;
    *(uint4*)&Bg[r0 * 32 + c0] = g0;
    *(uint4*)&Bg[(r0 + 64) * 32 + c0] = g1;
    __syncthreads();
    bf16x8 af[4], bif[4], bgf[4];
#pragma unroll
    for (int i = 0; i < 4; i++)
      af[i] = *(const bf16x8*)&As[(wm + i * 16 + l16) * 32 + quad * 8];
#pragma unroll
    for (int j = 0; j < 4; j++) {
      bif[j] = *(const bf16x8*)&Bi[(wn + j * 16 + l16) * 32 + quad * 8];
      bgf[j] = *(const bf16x8*)&Bg[(wn + j * 16 + l16) * 32 + quad * 8];
    }
#pragma unroll
    for (int i = 0; i < 4; i++)
#pragma unroll
      for (int j = 0; j < 4; j++) {
        ai[i][j] = MFMA_BF16(af[i], bif[j], ai[i][j]);
        ag[i][j] = MFMA_BF16(af[i], bgf[j], ag[i][j]);
      }
  }
#pragma unroll
  for (int j = 0; j < 4; j++) {
    const int col = n0 + wn + j * 16 + l16;
    const float bvi = bi[col];
    const float bvg = bg[col];
#pragma unroll
    for (int i = 0; i < 4; i++) {
      const size_t row = m0 + wm + i * 16 + quad * 4;
#pragma unroll
      for (int v = 0; v < 4; v++) {
        const float xi = ai[i][j][v] + bvi;
        const float xg = ag[i][j][v] + bvg;
        C[(row + v) * N + col] = tanhf(xi) * (1.0f / (1.0f + __expf(-xg)));
      }
    }
  }
}

// Per-(b,h) attention: one wave does a full 64x64x64 head (bf16 ws tensors).
// O may alias Qh: per-block regions are disjoint; Q fully staged to LDS before stores.
__global__ __launch_bounds__(64) void attn_head(const bf16_t* Qh,
                                                const bf16_t* Kh,
                                                const bf16_t* Vh,
                                                bf16_t* O,
                                                const int* __restrict__ seq_mask) {
  const int B = 1280, D = 512;
  const int b = blockIdx.x >> 3, h = blockIdx.x & 7;
  const int lane = threadIdx.x;
  __shared__ __align__(16) bf16_t Qs[64 * 64];
  __shared__ __align__(16) bf16_t Ks[64 * 64];
  __shared__ __align__(16) bf16_t VT[64 * 64];  // V transposed: VT[d][k]
  bf16_t* Ps = Qs;                              // reuse Q tile for P
  const size_t cb = (size_t)h * 64;
  for (int idx = lane; idx < 512; idx += 64) {
    const int r = idx >> 3, cg = (idx & 7) << 3;
    const size_t go = (size_t)(r * B + b) * D + cb + cg;
    *(uint4*)&Qs[r * 64 + cg] = *(const uint4*)&Qh[go];
    *(uint4*)&Ks[r * 64 + cg] = *(const uint4*)&Kh[go];
    uint4 vv = *(const uint4*)&Vh[go];
    const bf16_t* vp = (const bf16_t*)&vv;
#pragma unroll
    for (int jj = 0; jj < 8; jj++) VT[(cg + jj) * 64 + r] = vp[jj];
  }
  __syncthreads();
  const int quad = lane >> 4, l16 = lane & 15;
  f32x4 sc[4][4] = {};
#pragma unroll
  for (int ks = 0; ks < 2; ks++) {
    bf16x8 qa[4], kb[4];
#pragma unroll
    for (int i = 0; i < 4; i++)
      qa[i] = *(const bf16x8*)&Qs[(i * 16 + l16) * 64 + ks * 32 + quad * 8];
#pragma unroll
    for (int j = 0; j < 4; j++)
      kb[j] = *(const bf16x8*)&Ks[(j * 16 + l16) * 64 + ks * 32 + quad * 8];
#pragma unroll
    for (int i = 0; i < 4; i++)
#pragma unroll
      for (int j = 0; j < 4; j++)
        sc[i][j] = MFMA_BF16(qa[i], kb[j], sc[i][j]);
  }
  const bool causal = (seq_mask[0] != 0);
  __syncthreads();  // done reading Qs; about to overwrite with P
  // softmax per row; C-layout: row = i*16 + quad*4 + v, col = j*16 + l16
#pragma unroll
  for (int i = 0; i < 4; i++) {
#pragma unroll
    for (int v = 0; v < 4; v++) {
      const int r = i * 16 + quad * 4 + v;
      float sv[4];
      float mx = -3e38f;
#pragma unroll
      for (int j = 0; j < 4; j++) {
        const int c = j * 16 + l16;
        float s = sc[i][j][v];
        if (causal && c > r) s = -3e38f;
        sv[j] = s;
        mx = fmaxf(mx, s);
      }
#pragma unroll
      for (int m = 1; m < 16; m <<= 1) mx = fmaxf(mx, __shfl_xor(mx, m, 16));
      float sum = 0.f;
#pragma unroll
      for (int j = 0; j < 4; j++) {
        const float e = (sv[j] <= -1e38f) ? 0.f : __expf(sv[j] - mx);
        sv[j] = e;
        sum += e;
      }
#pragma unroll
      for (int m = 1; m < 16; m <<= 1) sum += __shfl_xor(sum, m, 16);
      const float inv = 1.0f / sum;
#pragma unroll
      for (int j = 0; j < 4; j++)
        Ps[r * 64 + j * 16 + l16] = __float2bfloat16(sv[j] * inv);
    }
  }
  __syncthreads();
  f32x4 oc[4][4] = {};
#pragma unroll
  for (int ks = 0; ks < 2; ks++) {
    bf16x8 pf[4], vf[4];
#pragma unroll
    for (int i = 0; i < 4; i++)
      pf[i] = *(const bf16x8*)&Ps[(i * 16 + l16) * 64 + ks * 32 + quad * 8];
#pragma unroll
    for (int j = 0; j < 4; j++)
      vf[j] = *(const bf16x8*)&VT[(j * 16 + l16) * 64 + ks * 32 + quad * 8];
#pragma unroll
    for (int i = 0; i < 4; i++)
#pragma unroll
      for (int j = 0; j < 4; j++)
        oc[i][j] = MFMA_BF16(pf[i], vf[j], oc[i][j]);
  }
#pragma unroll
  for (int i = 0; i < 4; i++)
#pragma unroll
    for (int j = 0; j < 4; j++) {
      const int c = j * 16 + l16;
#pragma unroll
      for (int v = 0; v < 4; v++) {
        const int r = i * 16 + quad * 4 + v;
        O[(size_t)(r * B + b) * D + cb + c] = __float2bfloat16(oc[i][j][v]);
      }
    }
}

extern "C" void kernel_launch(void* const* d_in, const int* in_sizes, int n_in,
                              void* d_out, int out_size, void* d_ws, size_t ws_size,
                              hipStream_t stream) {
  const float* query = (const float*)d_in[0];
  const float* key_ = (const float*)d_in[1];
  const float* value = (const float*)d_in[2];
  // d_in[3] = attn_mask: unused by the reference (it builds tmask from seq_mask)
  const float* Wq = (const float*)d_in[4];
  const float* bq = (const float*)d_in[5];
  const float* Wk = (const float*)d_in[6];
  const float* bk = (const float*)d_in[7];
  const float* Wv = (const float*)d_in[8];
  const float* bv = (const float*)d_in[9];
  const float* Wo = (const float*)d_in[10];
  const float* bo = (const float*)d_in[11];
  const float* Wti = (const float*)d_in[12];
  const float* bti = (const float*)d_in[13];
  const float* Wtg = (const float*)d_in[14];
  const float* btg = (const float*)d_in[15];
  const int* seq_mask = (const int*)d_in[16];
  float* out = (float*)d_out;

  const size_t M = 81920;  // L * A * S = 64*64*20
  const size_t buf = M * 512;
  bf16_t* Qh = (bf16_t*)d_ws;
  bf16_t* Kh = Qh + buf;
  bf16_t* Vh = Kh + buf;
  bf16_t* Ob = Qh;  // attention output aliases Qh (per-block disjoint r/w)
  bf16_t* Ta = Kh;  // t_attn overwrites Kh (dead after attention)

  dim3 gg(640, 4), gb(256);
  hipLaunchKernelGGL(gemm_f32, gg, gb, 0, stream, query, Wq, bq, Qh, 0.125f);
  hipLaunchKernelGGL(gemm_f32, gg, gb, 0, stream, key_, Wk, bk, Kh, 1.0f);
  hipLaunchKernelGGL(gemm_f32, gg, gb, 0, stream, value, Wv, bv, Vh, 1.0f);
  hipLaunchKernelGGL(attn_head, dim3(10240), dim3(64), 0, stream, Qh, Kh, Vh, Ob, seq_mask);
  hipLaunchKernelGGL(gemm_abf16, gg, gb, 0, stream, Ob, Wo, bo, Ta);
  hipLaunchKernelGGL(gemm_gate, gg, gb, 0, stream, Ta, Wti, bti, Wtg, btg, out);
}